// Round 7
// baseline (2554.495 us; speedup 1.0000x reference)
//
#include <hip/hip_runtime.h>
#include <cstdio>

// ============================================================================
// ROUND 21: attention is LDS-PIPE-THROUGHPUT bound, not latency bound.
// R20 post-mortem: occupancy 2x'd (11.5->20.8%) but time unchanged (463us),
// VALUBusy 40%. Per-CU LDS pipe demand ~3-4x SIMD FMA demand (QK 64 b64 + 64
// b128, PV 96 b128, V-transpose 8-way-conflict writes = 3.38e7 counter).
// Fix: K and V read DIRECTLY from global (VMEM pipe, L1/L2-resident 16KB
// tiles, coalesced 256B wave footprints). P stays in registers; o_part[2][64]
// accumulated per-thread over its 4 m-cols; one-time 16-lane shfl_xor reduce
// at the end. Zero barriers in main loop, zero K/V/P LDS traffic. Only Q
// broadcast b64 reads stay on LDS. VGPR ~190, launch_bounds(256,2).
// Convs unchanged from R19/R20.
// ============================================================================

// Keeps the harness-stub identifier name (unused utility).
__global__ __launch_bounds__(256) void CrossModalityPositionAttention_56556129354448_kernel(
    float* dst, float val, int n)
{
  const int i = blockIdx.x * 256 + threadIdx.x;
  if (i < n) dst[i] = val;
}

// ---------------------------------------------------------------------------
// DPP lane-shift helpers (conv halo).
__device__ __forceinline__ float dpp_left(float x) {
  return __int_as_float(__builtin_amdgcn_update_dpp(
      0, __float_as_int(x), 0x111, 0xF, 0xF, true));   // row_shr:1
}
__device__ __forceinline__ float dpp_right(float x) {
  return __int_as_float(__builtin_amdgcn_update_dpp(
      0, __float_as_int(x), 0x101, 0xF, 0xF, true));   // row_shl:1
}

#define CTROWS 18
#define CTSTR  64
#define CTSZ   (CTROWS * CTSTR)   // 1152 floats

// ---------------------------------------------------------------------------
// Fused q/k/v conv3x3 + BN + ReLU (unchanged from R19).
__global__ __launch_bounds__(256, 2) void convqkv_f32(
    const float* __restrict__ f1, const float* __restrict__ f2,
    const float* __restrict__ q_w, const float* __restrict__ q_b,
    const float* __restrict__ q_g, const float* __restrict__ q_be,
    const float* __restrict__ q_m, const float* __restrict__ q_va,
    const float* __restrict__ k_w, const float* __restrict__ k_b,
    const float* __restrict__ k_g, const float* __restrict__ k_be,
    const float* __restrict__ k_m, const float* __restrict__ k_va,
    const float* __restrict__ v_w, const float* __restrict__ v_b,
    const float* __restrict__ v_g, const float* __restrict__ v_be,
    const float* __restrict__ v_m, const float* __restrict__ v_va,
    float* __restrict__ qo, float* __restrict__ ko, float* __restrict__ vo)
{
  __shared__ float tA[2][CTSZ];
  __shared__ float tB[2][CTSZ];
  __shared__ float wlds[112];

  const int b   = blockIdx.z;
  const int co0 = blockIdx.y * 2;
  const int y0  = blockIdx.x * 16;
  const int t   = threadIdx.x;
  const int ry  = t >> 4;
  const int xg  = t & 15;
  const int x0  = xg * 4;

  float qs[2], qsh[2], ks[2], ksh[2], vs[2], vsh[2];
  #pragma unroll
  for (int cc = 0; cc < 2; ++cc) {
    const int c = co0 + cc;
    float iv;
    iv = q_g[c] * rsqrtf(q_va[c] + 1e-5f);
    qs[cc] = iv; qsh[cc] = q_b[c] * iv + q_be[c] - q_m[c] * iv;
    iv = k_g[c] * rsqrtf(k_va[c] + 1e-5f);
    ks[cc] = iv; ksh[cc] = k_b[c] * iv + k_be[c] - k_m[c] * iv;
    iv = v_g[c] * rsqrtf(v_va[c] + 1e-5f);
    vs[cc] = iv; vsh[cc] = v_b[c] * iv + v_be[c] - v_m[c] * iv;
  }

  const float* srcA = f1 + (size_t)b * 256 * 4096;
  const float* srcB = f2 + (size_t)b * 256 * 4096;

  float4 rA[2][2], rB[2][2];
  const int row0 = t >> 4;
  const int row1 = 16 + (t >> 4);
  const int grp  = t & 15;

  const int wseg = t / 18;
  const int wkk  = t - wseg * 18;
  const float* wptr = (wseg < 2) ? q_w : ((wseg < 4) ? k_w : v_w);
  const int wbase0 = (co0 + (wseg & 1)) * 256 * 9 + wkk;
  float wreg = 0.f;

  #define LOADREGS(R)                                                         \
    {                                                                         \
      _Pragma("unroll")                                                       \
      for (int s = 0; s < 2; ++s) {                                           \
        const size_t cb = (size_t)((R) * 2 + s) * 4096;                       \
        {                                                                     \
          const int gy = y0 - 1 + row0;                                       \
          float4 a = make_float4(0.f, 0.f, 0.f, 0.f);                         \
          float4 bb = make_float4(0.f, 0.f, 0.f, 0.f);                        \
          if (gy >= 0 && gy <= 63) {                                          \
            a  = *(const float4*)(srcA + cb + gy * 64 + grp * 4);             \
            bb = *(const float4*)(srcB + cb + gy * 64 + grp * 4);             \
          }                                                                   \
          rA[s][0] = a; rB[s][0] = bb;                                        \
        }                                                                     \
        if (t < 32) {                                                         \
          const int gy = y0 - 1 + row1;                                       \
          float4 a = make_float4(0.f, 0.f, 0.f, 0.f);                         \
          float4 bb = make_float4(0.f, 0.f, 0.f, 0.f);                        \
          if (gy >= 0 && gy <= 63) {                                          \
            a  = *(const float4*)(srcA + cb + gy * 64 + grp * 4);             \
            bb = *(const float4*)(srcB + cb + gy * 64 + grp * 4);             \
          }                                                                   \
          rA[s][1] = a; rB[s][1] = bb;                                        \
        }                                                                     \
      }                                                                       \
      if (t < 108) wreg = wptr[wbase0 + (R) * 18];                            \
    }

  float accQ[2][4] = {{0.f}}, accK[2][4] = {{0.f}}, accV[2][4] = {{0.f}};

  LOADREGS(0);

  for (int r = 0; r < 128; ++r) {
    __syncthreads();
    #pragma unroll
    for (int s = 0; s < 2; ++s) {
      *(float4*)(&tA[s][row0 * CTSTR + grp * 4]) = rA[s][0];
      *(float4*)(&tB[s][row0 * CTSTR + grp * 4]) = rB[s][0];
      if (t < 32) {
        *(float4*)(&tA[s][row1 * CTSTR + grp * 4]) = rA[s][1];
        *(float4*)(&tB[s][row1 * CTSTR + grp * 4]) = rB[s][1];
      }
    }
    if (t < 108) wlds[t] = wreg;
    __syncthreads();
    if (r < 127) LOADREGS(r + 1);

    #pragma unroll
    for (int s = 0; s < 2; ++s) {
      #pragma unroll
      for (int ky = 0; ky < 3; ++ky) {
        const float4 a4 = *(const float4*)(&tA[s][(ry + ky) * CTSTR + x0]);
        const float4 b4 = *(const float4*)(&tB[s][(ry + ky) * CTSTR + x0]);
        const float ca[6] = {dpp_left(a4.w), a4.x, a4.y, a4.z, a4.w, dpp_right(a4.x)};
        const float cb[6] = {dpp_left(b4.w), b4.x, b4.y, b4.z, b4.w, dpp_right(b4.x)};
        #pragma unroll
        for (int cc = 0; cc < 2; ++cc) {
          const int wb = cc * 18 + s * 9 + ky * 3;
          const float q0 = wlds[wb],      q1 = wlds[wb + 1],      q2 = wlds[wb + 2];
          const float k0 = wlds[36 + wb], k1 = wlds[36 + wb + 1], k2 = wlds[36 + wb + 2];
          const float v0 = wlds[72 + wb], v1 = wlds[72 + wb + 1], v2 = wlds[72 + wb + 2];
          #pragma unroll
          for (int px = 0; px < 4; ++px) {
            accQ[cc][px] += cb[px] * q0 + cb[px + 1] * q1 + cb[px + 2] * q2;
            accK[cc][px] += ca[px] * k0 + ca[px + 1] * k1 + ca[px + 2] * k2;
            accV[cc][px] += ca[px] * v0 + ca[px + 1] * v1 + ca[px + 2] * v2;
          }
        }
      }
    }
  }

  const size_t ob = ((size_t)b * 64 + co0) * 4096 + (size_t)(y0 + ry) * 64 + x0;
  #pragma unroll
  for (int cc = 0; cc < 2; ++cc) {
    float4 o;
    o.x = fmaxf(accQ[cc][0] * qs[cc] + qsh[cc], 0.f);
    o.y = fmaxf(accQ[cc][1] * qs[cc] + qsh[cc], 0.f);
    o.z = fmaxf(accQ[cc][2] * qs[cc] + qsh[cc], 0.f);
    o.w = fmaxf(accQ[cc][3] * qs[cc] + qsh[cc], 0.f);
    *(float4*)(qo + ob + (size_t)cc * 4096) = o;
    o.x = fmaxf(accK[cc][0] * ks[cc] + ksh[cc], 0.f);
    o.y = fmaxf(accK[cc][1] * ks[cc] + ksh[cc], 0.f);
    o.z = fmaxf(accK[cc][2] * ks[cc] + ksh[cc], 0.f);
    o.w = fmaxf(accK[cc][3] * ks[cc] + ksh[cc], 0.f);
    *(float4*)(ko + ob + (size_t)cc * 4096) = o;
    o.x = fmaxf(accV[cc][0] * vs[cc] + vsh[cc], 0.f);
    o.y = fmaxf(accV[cc][1] * vs[cc] + vsh[cc], 0.f);
    o.z = fmaxf(accV[cc][2] * vs[cc] + vsh[cc], 0.f);
    o.w = fmaxf(accV[cc][3] * vs[cc] + vsh[cc], 0.f);
    *(float4*)(vo + ob + (size_t)cc * 4096) = o;
  }
}

// ---------------------------------------------------------------------------
// Flash attention, fp32, K/V direct-from-global (VMEM pipe), P in registers.
// 32 queries/block, grid 512 = 2 blocks/CU.
// Block decode: b = (lin&7)>>1 (batch pinned per XCD-pair, K+V 2MB in 4MB L2),
// nb = (lin>>3)*2 | (lin&1), n0 = 32*nb.
// Thread (ng = t>>4, mg = t&15): rows n = 2ng+{0,1}, m-cols 4mg+{0..3}.
// o_part[2][64] per thread accumulates over its own m-cols across all tiles;
// 16-lane shfl_xor reduce across mg once at the end. No main-loop barriers.
__global__ __launch_bounds__(256, 2) void attention_flash_f32(
    const float* __restrict__ q, const float* __restrict__ k,
    const float* __restrict__ v, float* __restrict__ f)
{
  __shared__ float qt_lds[64 * 36];   // Q [c][n], stride 36 (9 KB)

  const int lin = blockIdx.x;
  const int b  = (lin & 7) >> 1;
  const int nb = ((lin >> 3) << 1) | (lin & 1);   // 0..127
  const int n0 = nb * 32;

  const int t = threadIdx.x;
  const int mg = t & 15;
  const int ng = t >> 4;    // 0..15

  const float* qb = q + (size_t)b * 64 * 4096;
  const float* kb = k + (size_t)b * 64 * 4096;
  const float* vb = v + (size_t)b * 64 * 4096;

  // ---- stage Q tile [c][n0..n0+31] into qt_lds[c][n], stride 36
  {
    const int nn = t & 7;
    const int c0 = t >> 3;
    #pragma unroll
    for (int p = 0; p < 2; ++p) {
      const int c = c0 + p * 32;
      const float4 val = *(const float4*)(qb + (size_t)c * 4096 + n0 + nn * 4);
      *(float4*)(qt_lds + c * 36 + nn * 4) = val;
    }
  }
  __syncthreads();   // only barrier before epilogue

  float o0[64], o1[64];
  #pragma unroll
  for (int c = 0; c < 64; ++c) { o0[c] = 0.f; o1[c] = 0.f; }
  float m0r = -1e30f, m1r = -1e30f, l0 = 0.f, l1 = 0.f;

  const float* kcol = kb + mg * 4;
  const float* vcol = vb + mg * 4;

  for (int tile = 0; tile < 64; ++tile) {
    const int m0 = tile * 64;
    const float* kp = kcol + m0;
    const float* vp = vcol + m0;

    // ---- QK: s[i][j] = sum_c Q[c][2ng+i] * K[c][4mg+j]  (K from global/L1)
    float s00 = 0.f, s01 = 0.f, s02 = 0.f, s03 = 0.f;
    float s10 = 0.f, s11 = 0.f, s12 = 0.f, s13 = 0.f;
    #pragma unroll
    for (int c = 0; c < 64; ++c) {
      const float4 k4 = *(const float4*)(kp + (size_t)c * 4096);
      const float2 q2 = *(const float2*)(qt_lds + c * 36 + 2 * ng);
      s00 = fmaf(q2.x, k4.x, s00); s01 = fmaf(q2.x, k4.y, s01);
      s02 = fmaf(q2.x, k4.z, s02); s03 = fmaf(q2.x, k4.w, s03);
      s10 = fmaf(q2.y, k4.x, s10); s11 = fmaf(q2.y, k4.y, s11);
      s12 = fmaf(q2.y, k4.z, s12); s13 = fmaf(q2.y, k4.w, s13);
    }

    // ---- online softmax (across the 16 mg-lanes; intra-wave)
    float rm0 = fmaxf(fmaxf(s00, s01), fmaxf(s02, s03));
    rm0 = fmaxf(rm0, __shfl_xor(rm0, 1));
    rm0 = fmaxf(rm0, __shfl_xor(rm0, 2));
    rm0 = fmaxf(rm0, __shfl_xor(rm0, 4));
    rm0 = fmaxf(rm0, __shfl_xor(rm0, 8));
    float rm1 = fmaxf(fmaxf(s10, s11), fmaxf(s12, s13));
    rm1 = fmaxf(rm1, __shfl_xor(rm1, 1));
    rm1 = fmaxf(rm1, __shfl_xor(rm1, 2));
    rm1 = fmaxf(rm1, __shfl_xor(rm1, 4));
    rm1 = fmaxf(rm1, __shfl_xor(rm1, 8));

    const float mn0 = fmaxf(m0r, rm0);
    const float mn1 = fmaxf(m1r, rm1);
    const float al0 = __expf(m0r - mn0);
    const float al1 = __expf(m1r - mn1);
    m0r = mn0; m1r = mn1;

    const float p00 = __expf(s00 - mn0), p01 = __expf(s01 - mn0);
    const float p02 = __expf(s02 - mn0), p03 = __expf(s03 - mn0);
    const float p10 = __expf(s10 - mn1), p11 = __expf(s11 - mn1);
    const float p12 = __expf(s12 - mn1), p13 = __expf(s13 - mn1);

    float rs0 = p00 + p01 + p02 + p03;
    rs0 += __shfl_xor(rs0, 1);
    rs0 += __shfl_xor(rs0, 2);
    rs0 += __shfl_xor(rs0, 4);
    rs0 += __shfl_xor(rs0, 8);
    float rs1 = p10 + p11 + p12 + p13;
    rs1 += __shfl_xor(rs1, 1);
    rs1 += __shfl_xor(rs1, 2);
    rs1 += __shfl_xor(rs1, 4);
    rs1 += __shfl_xor(rs1, 8);
    l0 = al0 * l0 + rs0;
    l1 = al1 * l1 + rs1;

    // ---- PV fused with rescale: o[i][c] = o[i][c]*al + sum_j p[i][j]*V[c][4mg+j]
    #pragma unroll
    for (int c = 0; c < 64; ++c) {
      const float4 v4 = *(const float4*)(vp + (size_t)c * 4096);
      float a0 = o0[c] * al0;
      a0 = fmaf(p00, v4.x, a0); a0 = fmaf(p01, v4.y, a0);
      a0 = fmaf(p02, v4.z, a0); a0 = fmaf(p03, v4.w, a0);
      o0[c] = a0;
      float a1 = o1[c] * al1;
      a1 = fmaf(p10, v4.x, a1); a1 = fmaf(p11, v4.y, a1);
      a1 = fmaf(p12, v4.z, a1); a1 = fmaf(p13, v4.w, a1);
      o1[c] = a1;
    }
  }

  // ---- cross-mg reduction (16 lanes), normalize
  #pragma unroll
  for (int c = 0; c < 64; ++c) {
    float a0 = o0[c], a1 = o1[c];
    a0 += __shfl_xor(a0, 1); a1 += __shfl_xor(a1, 1);
    a0 += __shfl_xor(a0, 2); a1 += __shfl_xor(a1, 2);
    a0 += __shfl_xor(a0, 4); a1 += __shfl_xor(a1, 4);
    a0 += __shfl_xor(a0, 8); a1 += __shfl_xor(a1, 8);
    o0[c] = a0; o1[c] = a1;
  }
  const float inv0 = 1.f / l0;
  const float inv1 = 1.f / l1;

  // ---- epilogue: write [c][n] to LDS (lane mg owns c = 4mg..4mg+3), store
  __syncthreads();   // Q reads done; reuse qt_lds
  #pragma unroll
  for (int j = 0; j < 4; ++j) {
    const int c = 4 * mg + j;
    qt_lds[c * 36 + 2 * ng + 0] = o0[c] * inv0;
    qt_lds[c * 36 + 2 * ng + 1] = o1[c] * inv1;
  }
  __syncthreads();
  {
    const int c = t >> 2;   // 0..63
    #pragma unroll
    for (int r = 0; r < 2; ++r) {
      const int f4i = (t & 3) + 4 * r;   // 0..7
      *(float4*)(f + ((size_t)b * 64 + c) * 4096 + n0 + f4i * 4) =
          *(const float4*)(qt_lds + c * 36 + f4i * 4);
    }
  }
}

// ---------------------------------------------------------------------------
// conv_r (unchanged from R19).
__global__ __launch_bounds__(256, 4) void conv_r_f32(
    const float* __restrict__ fin, const float* __restrict__ w,
    const float* __restrict__ bi, const float* __restrict__ g,
    const float* __restrict__ be, const float* __restrict__ mu,
    const float* __restrict__ va, const float* __restrict__ res,
    float* __restrict__ out)
{
  __shared__ float tA[2][CTSZ];
  __shared__ float wlds[80];

  const int b   = blockIdx.z;
  const int co0 = blockIdx.y * 4;
  const int y0  = blockIdx.x * 16;
  const int t   = threadIdx.x;
  const int ry  = t >> 4;
  const int xg  = t & 15;
  const int x0  = xg * 4;

  float sc[4], sh[4];
  #pragma unroll
  for (int cc = 0; cc < 4; ++cc) {
    const int c = co0 + cc;
    const float iv = g[c] * rsqrtf(va[c] + 1e-5f);
    sc[cc] = iv; sh[cc] = bi[c] * iv + be[c] - mu[c] * iv;
  }

  const float* srcA = fin + (size_t)b * 64 * 4096;
  float4 rA[2][2];
  const int row0 = t >> 4;
  const int row1 = 16 + (t >> 4);
  const int grp  = t & 15;

  const int wseg = t / 18;
  const int wkk  = t - wseg * 18;
  const int wbase0 = (co0 + wseg) * 64 * 9 + wkk;
  float wreg = 0.f;

  #define LOADR(R)                                                            \
    {                                                                         \
      _Pragma("unroll")                                                       \
      for (int s = 0; s < 2; ++s) {                                           \
        const size_t cb = (size_t)((R) * 2 + s) * 4096;                       \
        {                                                                     \
          const int gy = y0 - 1 + row0;                                       \
          float4 a = make_float4(0.f, 0.f, 0.f, 0.f);                         \
          if (gy >= 0 && gy <= 63)                                            \
            a = *(const float4*)(srcA + cb + gy * 64 + grp * 4);              \
          rA[s][0] = a;                                                       \
        }                                                                     \
        if (t < 32) {                                                         \
          const int gy = y0 - 1 + row1;                                       \
          float4 a = make_float4(0.f, 0.f, 0.f, 0.f);                         \
          if (gy >= 0 && gy <= 63)                                            \
            a = *(const float4*)(srcA + cb + gy * 64 + grp * 4);              \
          rA[s][1] = a;                                                       \
        }                                                                     \
      }                                                                       \
      if (t < 72) wreg = w[wbase0 + (R) * 18];                                \
    }

  float acc[4][4] = {{0.f}};
  LOADR(0);

  for (int r = 0; r < 32; ++r) {
    __syncthreads();
    #pragma unroll
    for (int s = 0; s < 2; ++s) {
      *(float4*)(&tA[s][row0 * CTSTR + grp * 4]) = rA[s][0];
      if (t < 32)
        *(float4*)(&tA[s][row1 * CTSTR + grp * 4]) = rA[s][1];
    }
    if (t < 72) wlds[t] = wreg;
    __syncthreads();
    if (r < 31) LOADR(r + 1);

    #pragma unroll
    for (int s = 0; s < 2; ++s) {
      #pragma unroll
      for (int ky = 0; ky < 3; ++ky) {
        const float4 a4 = *(const float4*)(&tA[s][(ry + ky) * CTSTR + x0]);
        const float ca[6] = {dpp_left(a4.w), a4.x, a4.y, a4.z, a4.w, dpp_right(a4.x)};
        #pragma unroll
        for (int cc = 0; cc < 4; ++cc) {
          const int wb = cc * 18 + s * 9 + ky * 3;
          const float w0 = wlds[wb], w1 = wlds[wb + 1], w2 = wlds[wb + 2];
          #pragma unroll
          for (int px = 0; px < 4; ++px)
            acc[cc][px] += ca[px] * w0 + ca[px + 1] * w1 + ca[px + 2] * w2;
        }
      }
    }
  }

  const size_t ob = ((size_t)b * 256 + co0) * 4096 + (size_t)(y0 + ry) * 64 + x0;
  #pragma unroll
  for (int cc = 0; cc < 4; ++cc) {
    const float4 rv = *(const float4*)(res + ob + (size_t)cc * 4096);
    float4 o;
    o.x = rv.x + fmaxf(acc[cc][0] * sc[cc] + sh[cc], 0.f);
    o.y = rv.y + fmaxf(acc[cc][1] * sc[cc] + sh[cc], 0.f);
    o.z = rv.z + fmaxf(acc[cc][2] * sc[cc] + sh[cc], 0.f);
    o.w = rv.w + fmaxf(acc[cc][3] * sc[cc] + sh[cc], 0.f);
    *(float4*)(out + ob + (size_t)cc * 4096) = o;
  }
}

// ---------------------------------------------------------------------------
extern "C" void kernel_launch(void* const* d_in, const int* in_sizes, int n_in,
                              void* d_out, int out_size, void* d_ws, size_t ws_size,
                              hipStream_t stream) {
  const float* f1 = (const float*)d_in[0];
  const float* f2 = (const float*)d_in[1];
  const float* qw = (const float*)d_in[2];  const float* qb = (const float*)d_in[3];
  const float* qg = (const float*)d_in[4];  const float* qbe = (const float*)d_in[5];
  const float* qm = (const float*)d_in[6];  const float* qv = (const float*)d_in[7];
  const float* kw = (const float*)d_in[8];  const float* kb = (const float*)d_in[9];
  const float* kg = (const float*)d_in[10]; const float* kbe = (const float*)d_in[11];
  const float* km = (const float*)d_in[12]; const float* kv = (const float*)d_in[13];
  const float* vw = (const float*)d_in[14]; const float* vb = (const float*)d_in[15];
  const float* vg = (const float*)d_in[16]; const float* vbe = (const float*)d_in[17];
  const float* vm = (const float*)d_in[18]; const float* vv = (const float*)d_in[19];
  const float* rw = (const float*)d_in[20]; const float* rb = (const float*)d_in[21];
  const float* rg = (const float*)d_in[22]; const float* rbe = (const float*)d_in[23];
  const float* rm = (const float*)d_in[24]; const float* rv = (const float*)d_in[25];

  hipStreamCaptureStatus cap = hipStreamCaptureStatusNone;
  unsigned long long capid = 0;
  const hipError_t ce = hipStreamGetCaptureInfo(stream, &cap, &capid);
  const bool capturing = (ce == hipSuccess) && (cap != hipStreamCaptureStatusNone);

  // Workspace: q,k,v,f fp32 [4][64][4096] = 4 MB each (ws_size = 256 MB).
  const size_t SZ1 = (size_t)4 * 64 * 4096 * 4;
  float* qp = (float*)d_ws;
  float* kp = (float*)((char*)d_ws + SZ1);
  float* vp = (float*)((char*)d_ws + 2 * SZ1);
  float* fp = (float*)((char*)d_ws + 3 * SZ1);

  convqkv_f32<<<dim3(4, 32, 4), 256, 0, stream>>>(
      f1, f2,
      qw, qb, qg, qbe, qm, qv,
      kw, kb, kg, kbe, km, kv,
      vw, vb, vg, vbe, vm, vv,
      qp, kp, vp);
  attention_flash_f32<<<dim3(512), 256, 0, stream>>>(qp, kp, vp, fp);
  conv_r_f32<<<dim3(4, 64, 4), 256, 0, stream>>>(fp, rw, rb, rg, rbe, rm, rv,
                                                 f1, (float*)d_out);

  if (!capturing) {
    const hipError_t le = hipGetLastError();
    const hipError_t se = hipStreamSynchronize(stream);
    float h[4] = {0, 0, 0, 0};
    (void)hipMemcpy(h, d_out, 16, hipMemcpyDeviceToHost);
    fprintf(stderr,
        "ATHENA_R21 attn-direct-KV le=%d sync=%d out=[%g %g %g %g]\n",
        (int)le, (int)se, h[0], h[1], h[2], h[3]);
    fflush(stderr);
  }
}